// Round 8
// baseline (471.767 us; speedup 1.0000x reference)
//
#include <hip/hip_runtime.h>
#include <math.h>

// ---------------------------------------------------------------------------
// N=100000, E=1600000, dims 128. Round 8:
//  - CSR build via LDS-privatized counting sort (k_hist + k_scanS): no
//    device-scope atomics (k_cnt's 78 us was memory-side RMW bound).
//  - Rest unchanged: packed 4-B records, quarter-wave uint4 pull, bf16 MFMA
//    dense kernels.
// ---------------------------------------------------------------------------

typedef __attribute__((ext_vector_type(8))) short short8;   // 8 bf16 (4 VGPR)
typedef __attribute__((ext_vector_type(4))) float float4v;  // 4 fp32 acc

#define WQ_SCALE 32767.0f
#define WQ_INV   (1.0f / 32767.0f)

#define HRL2 14
#define HR (1 << HRL2)      // nodes per histogram range (64 KiB LDS of int)
#define NSLICE 64           // edge slices

__device__ __forceinline__ unsigned f2bf_pack(float a, float b) {
    unsigned ua = __float_as_uint(a);
    unsigned ub = __float_as_uint(b);
    ua += 0x7FFF + ((ua >> 16) & 1);   // RNE
    ub += 0x7FFF + ((ub >> 16) & 1);
    return (ua >> 16) | (ub & 0xFFFF0000u);
}

__device__ __forceinline__ unsigned short f2bf1(float a) {
    unsigned u = __float_as_uint(a);
    u += 0x7FFF + ((u >> 16) & 1);
    return (unsigned short)(u >> 16);
}

__device__ __forceinline__ float act_leaky_elu(float v) {
    float l = (v >= 0.0f) ? v : 0.01f * v;
    return (l > 0.0f) ? l : expm1f(l);
}

// B-fragment for mfma_16x16x32_bf16 from fp32 W[k][n] (row-major [128][128]).
__device__ __forceinline__ short8 load_bfrag(const float* __restrict__ W,
                                             int n, int k0) {
    union { short8 s8; unsigned u[4]; } r;
    #pragma unroll
    for (int j = 0; j < 4; ++j) {
        float a = W[(k0 + 2 * j) * 128 + n];
        float b = W[(k0 + 2 * j + 1) * 128 + n];
        r.u[j] = f2bf_pack(a, b);
    }
    return r.s8;
}

__device__ __forceinline__ short8 load_afrag_f32(const float* __restrict__ p) {
    float4 a = ((const float4*)p)[0];
    float4 b = ((const float4*)p)[1];
    union { short8 s8; unsigned u[4]; } r;
    r.u[0] = f2bf_pack(a.x, a.y); r.u[1] = f2bf_pack(a.z, a.w);
    r.u[2] = f2bf_pack(b.x, b.y); r.u[3] = f2bf_pack(b.z, b.w);
    return r.s8;
}

// ---------------- CSR build: LDS counting sort ----------------
// Block (s, r): histogram slice s's targets within node range r into LDS.
// rank[e] = local rank of edge within (bucket, slice). part[(r,s)] = partial
// histogram. Global atomics: none (LDS only).
__global__ __launch_bounds__(256)
void k_hist(const int* __restrict__ tgt, int* __restrict__ rank,
            int* __restrict__ part, int E, int R) {
    __shared__ int lh[HR];
    const int s = blockIdx.x / R;      // consecutive blocks share a slice -> L2 reuse
    const int r = blockIdx.x % R;
    for (int i = threadIdx.x; i < HR; i += 256) lh[i] = 0;
    __syncthreads();
    const int chunk = (E + NSLICE - 1) / NSLICE;
    const int lo = s * chunk;
    const int hi = min(lo + chunk, E);
    const int base = r << HRL2;
    for (int e = lo + threadIdx.x; e < hi; e += 256) {
        unsigned d = (unsigned)(tgt[e] - base);
        if (d < HR) rank[e] = atomicAdd(&lh[d], 1);
    }
    __syncthreads();
    int* pp = part + ((size_t)r * NSLICE + s) * HR;
    for (int i = threadIdx.x; i < 4096; i += 256)
        ((int4*)pp)[i] = ((const int4*)lh)[i];
}

// Exclusive scan over the NSLICE partials per bucket (in place), total -> cnti.
__global__ __launch_bounds__(256)
void k_scanS(int* __restrict__ part, int* __restrict__ cnti, int N, int R) {
    int idx = blockIdx.x * 256 + threadIdx.x;   // node id = r*HR + b
    if (idx >= (R << HRL2)) return;
    int r = idx >> HRL2;
    int b = idx & (HR - 1);
    int* p = part + ((size_t)r * NSLICE) * HR + b;
    int acc = 0;
    #pragma unroll 4
    for (int s = 0; s < NSLICE; ++s) {
        int v = p[(size_t)s * HR];
        p[(size_t)s * HR] = acc;
        acc += v;
    }
    if (idx < N) cnti[idx] = acc;
}

// ---- hierarchical exclusive scan over n ints (rowp from cnti) ----
__global__ __launch_bounds__(256)
void k_scan1(const int* __restrict__ in, int* __restrict__ out,
             int* __restrict__ blksum, int n) {
    __shared__ int sh[256];
    const int tid = threadIdx.x;
    const int idx = blockIdx.x * 1024 + tid * 4;
    int v0 = (idx + 0 < n) ? in[idx + 0] : 0;
    int v1 = (idx + 1 < n) ? in[idx + 1] : 0;
    int v2 = (idx + 2 < n) ? in[idx + 2] : 0;
    int v3 = (idx + 3 < n) ? in[idx + 3] : 0;
    int tsum = v0 + v1 + v2 + v3;
    sh[tid] = tsum;
    __syncthreads();
    #pragma unroll
    for (int off = 1; off < 256; off <<= 1) {
        int add = (tid >= off) ? sh[tid - off] : 0;
        __syncthreads();
        sh[tid] += add;
        __syncthreads();
    }
    int excl = sh[tid] - tsum;
    if (idx + 0 < n) out[idx + 0] = excl;
    if (idx + 1 < n) out[idx + 1] = excl + v0;
    if (idx + 2 < n) out[idx + 2] = excl + v0 + v1;
    if (idx + 3 < n) out[idx + 3] = excl + v0 + v1 + v2;
    if (tid == 255) blksum[blockIdx.x] = sh[255];
}

__global__ __launch_bounds__(128)
void k_scan2(int* __restrict__ blksum, int nb) {
    __shared__ int sh[128];
    const int tid = threadIdx.x;
    int orig = (tid < nb) ? blksum[tid] : 0;
    sh[tid] = orig;
    __syncthreads();
    #pragma unroll
    for (int off = 1; off < 128; off <<= 1) {
        int add = (tid >= off) ? sh[tid - off] : 0;
        __syncthreads();
        sh[tid] += add;
        __syncthreads();
    }
    if (tid < nb) blksum[tid] = sh[tid] - orig;
}

__global__ __launch_bounds__(256)
void k_scan3(int* __restrict__ out, const int* __restrict__ blksum, int n) {
    const int add = blksum[blockIdx.x];
    const int base = blockIdx.x * 1024 + threadIdx.x;
    #pragma unroll
    for (int i = 0; i < 4; ++i) {
        int idx = base + i * 256;
        if (idx < n) out[idx] += add;
    }
}

// atomic-free packed scatter: pos = rowp[t] + sliceoff + localrank
__global__ __launch_bounds__(256)
void k_scatterP(const int* __restrict__ ei, const float* __restrict__ ew,
                const int* __restrict__ rowp, const int* __restrict__ rank,
                const int* __restrict__ part, unsigned* __restrict__ recs,
                int E) {
    int e = blockIdx.x * 256 + threadIdx.x;
    if (e < E) {
        int t = ei[E + e];
        int chunk = (E + NSLICE - 1) / NSLICE;
        int s = e / chunk;
        int r = t >> HRL2;
        int off = part[((size_t)r * NSLICE + s) * HR + (t & (HR - 1))];
        int pos = rowp[t] + off + rank[e];
        unsigned wq = (unsigned)__builtin_rintf(ew[e] * WQ_SCALE);
        recs[pos] = (wq << 17) | (unsigned)ei[e];
    }
}

// ---- fallback path (N > 2^17): atomic count + wide records ----
__global__ __launch_bounds__(256)
void k_cnt(const int* __restrict__ ei, int* __restrict__ cnti,
           int* __restrict__ rank, int E) {
    int e = blockIdx.x * 256 + threadIdx.x;
    if (e < E) rank[e] = atomicAdd(&cnti[ei[E + e]], 1);
}

__global__ __launch_bounds__(256)
void k_scatterW(const int* __restrict__ ei, const float* __restrict__ ew,
                const int* __restrict__ rowp, const int* __restrict__ rank,
                int2* __restrict__ recs, int E) {
    int e = blockIdx.x * 256 + threadIdx.x;
    if (e < E) {
        int c = ei[E + e];
        int pos = rowp[c] + rank[e];
        recs[pos] = make_int2(ei[e], __float_as_int(ew[e]));
    }
}

template <bool PACKED>
__global__ __launch_bounds__(256)
void k_degsum(const int* __restrict__ rowp, const void* __restrict__ recs_,
              float* __restrict__ dis, int N) {
    int n = blockIdx.x * 256 + threadIdx.x;
    if (n >= N) return;
    int s = rowp[n], eE = rowp[n + 1];
    float d = 0.0f;
    if (PACKED) {
        const unsigned* recs = (const unsigned*)recs_;
        for (int e = s; e < eE; ++e) d += (float)(recs[e] >> 17) * WQ_INV;
    } else {
        const int2* recs = (const int2*)recs_;
        for (int e = s; e < eE; ++e) d += __int_as_float(recs[e].y);
    }
    dis[n] = (d > 0.0f) ? (1.0f / sqrtf(fmaxf(d, 1e-12f))) : 0.0f;
}

// ---------------- preprocessor GEMM: hb = bf16(x @ Wpre + bpre) ----------------
__global__ __launch_bounds__(256)
void k_pre(const float* __restrict__ x, const float* __restrict__ Wpre,
           const float* __restrict__ bpre, unsigned short* __restrict__ hb,
           int N) {
    const int lane = threadIdx.x & 63;
    const int wv = threadIdx.x >> 6;
    const int q = lane >> 4;
    const int m = lane & 15;
    const int cg = wv * 32;
    short8 B[2][4];
    #pragma unroll
    for (int ct = 0; ct < 2; ++ct)
        #pragma unroll
        for (int c = 0; c < 4; ++c)
            B[ct][c] = load_bfrag(Wpre, cg + ct * 16 + m, c * 32 + q * 8);
    const float b0 = bpre[cg + m];
    const float b1 = bpre[cg + 16 + m];
    const int rb = blockIdx.x * 128;
    #pragma unroll 2
    for (int rt = 0; rt < 8; ++rt) {
        int row = rb + rt * 16 + m;
        int rc = min(row, N - 1);
        const float* xp = x + (size_t)rc * 128 + q * 8;
        float4v a0 = {0.f, 0.f, 0.f, 0.f}, a1 = {0.f, 0.f, 0.f, 0.f};
        #pragma unroll
        for (int c = 0; c < 4; ++c) {
            short8 a = load_afrag_f32(xp + c * 32);
            a0 = __builtin_amdgcn_mfma_f32_16x16x32_bf16(a, B[0][c], a0, 0, 0, 0);
            a1 = __builtin_amdgcn_mfma_f32_16x16x32_bf16(a, B[1][c], a1, 0, 0, 0);
        }
        #pragma unroll
        for (int r = 0; r < 4; ++r) {
            int ro = rb + rt * 16 + q * 4 + r;
            if (ro < N) {
                hb[(size_t)ro * 128 + cg + m]      = f2bf1(a0[r] + b0);
                hb[(size_t)ro * 128 + cg + 16 + m] = f2bf1(a1[r] + b1);
            }
        }
    }
}

// ---------------- pull aggregation: quarter-wave rows, 4 edges/iter -----------
template <bool PACKED>
__global__ __launch_bounds__(256)
void k_pull(const int* __restrict__ rowp, const void* __restrict__ recs_,
            const float* __restrict__ dis, const uint4* __restrict__ hb4,
            uint4* __restrict__ agb4, uint4* __restrict__ mnb4, int N) {
    const int node = blockIdx.x * 4 + (threadIdx.x >> 6);
    if (node >= N) return;
    const int lane = threadIdx.x & 63;
    const int q4 = lane >> 4;          // quarter: which edge of the group of 4
    const int sub = lane & 15;         // uint4 index within the 16-uint4 row
    int s  = __builtin_amdgcn_readfirstlane(rowp[node]);
    int eE = __builtin_amdgcn_readfirstlane(rowp[node + 1]);
    const float dcol = dis[node];
    const float im = 1.0f / fmaxf((float)(eE - s), 1.0f);

    float aA[8], aM[8];
    #pragma unroll
    for (int i = 0; i < 8; ++i) { aA[i] = 0.f; aM[i] = 0.f; }

    #pragma unroll 2
    for (int e = s; e < eE; e += 4) {
        int el = e + q4;
        bool ok = el < eE;
        int el2 = ok ? el : (eE - 1);
        int src; float w;
        if (PACKED) {
            unsigned rv = ((const unsigned*)recs_)[el2];
            src = (int)(rv & 0x1FFFFu);
            w = (float)(rv >> 17) * WQ_INV;
        } else {
            int2 rv = ((const int2*)recs_)[el2];
            src = rv.x;
            w = __int_as_float(rv.y);
        }
        if (!ok) w = 0.f;
        float c = dis[src] * w;
        uint4 u = hb4[(size_t)src * 16 + sub];
        float f0 = __uint_as_float(u.x << 16);
        float f1 = __uint_as_float(u.x & 0xFFFF0000u);
        float f2 = __uint_as_float(u.y << 16);
        float f3 = __uint_as_float(u.y & 0xFFFF0000u);
        float f4 = __uint_as_float(u.z << 16);
        float f5 = __uint_as_float(u.z & 0xFFFF0000u);
        float f6 = __uint_as_float(u.w << 16);
        float f7 = __uint_as_float(u.w & 0xFFFF0000u);
        aA[0] = fmaf(c, f0, aA[0]); aM[0] = fmaf(w, f0, aM[0]);
        aA[1] = fmaf(c, f1, aA[1]); aM[1] = fmaf(w, f1, aM[1]);
        aA[2] = fmaf(c, f2, aA[2]); aM[2] = fmaf(w, f2, aM[2]);
        aA[3] = fmaf(c, f3, aA[3]); aM[3] = fmaf(w, f3, aM[3]);
        aA[4] = fmaf(c, f4, aA[4]); aM[4] = fmaf(w, f4, aM[4]);
        aA[5] = fmaf(c, f5, aA[5]); aM[5] = fmaf(w, f5, aM[5]);
        aA[6] = fmaf(c, f6, aA[6]); aM[6] = fmaf(w, f6, aM[6]);
        aA[7] = fmaf(c, f7, aA[7]); aM[7] = fmaf(w, f7, aM[7]);
    }

    #pragma unroll
    for (int i = 0; i < 8; ++i) {
        aA[i] += __shfl_xor(aA[i], 32, 64);
        aA[i] += __shfl_xor(aA[i], 16, 64);
        aM[i] += __shfl_xor(aM[i], 32, 64);
        aM[i] += __shfl_xor(aM[i], 16, 64);
    }

    if (q4 == 0) {
        uint4 o;
        o.x = f2bf_pack(aA[0] * dcol, aA[1] * dcol);
        o.y = f2bf_pack(aA[2] * dcol, aA[3] * dcol);
        o.z = f2bf_pack(aA[4] * dcol, aA[5] * dcol);
        o.w = f2bf_pack(aA[6] * dcol, aA[7] * dcol);
        agb4[(size_t)node * 16 + sub] = o;
    } else if (q4 == 1) {
        uint4 o;
        o.x = f2bf_pack(aM[0] * im, aM[1] * im);
        o.y = f2bf_pack(aM[2] * im, aM[3] * im);
        o.z = f2bf_pack(aM[4] * im, aM[5] * im);
        o.w = f2bf_pack(aM[6] * im, aM[7] * im);
        mnb4[(size_t)node * 16 + sub] = o;
    }
}

// ---------------- fused epilogue: out = act(A1@W1 + A2@W2 + b) -----------------
template <int ACT>
__global__ __launch_bounds__(256)
void k_final(const unsigned short* __restrict__ A1,
             const unsigned short* __restrict__ A2,
             const float* __restrict__ W1, const float* __restrict__ W2,
             const float* __restrict__ bias, float* __restrict__ out, int N) {
    const int lane = threadIdx.x & 63;
    const int wv = threadIdx.x >> 6;
    const int q = lane >> 4;
    const int m = lane & 15;
    const int cg = wv * 32;
    short8 B1[2][4], B2[2][4];
    #pragma unroll
    for (int ct = 0; ct < 2; ++ct)
        #pragma unroll
        for (int c = 0; c < 4; ++c) {
            B1[ct][c] = load_bfrag(W1, cg + ct * 16 + m, c * 32 + q * 8);
            B2[ct][c] = load_bfrag(W2, cg + ct * 16 + m, c * 32 + q * 8);
        }
    const float b0 = bias[cg + m];
    const float b1 = bias[cg + 16 + m];
    const int rb = blockIdx.x * 128;
    #pragma unroll 2
    for (int rt = 0; rt < 8; ++rt) {
        int row = rb + rt * 16 + m;
        int rc = min(row, N - 1);
        const short8* a1 = (const short8*)(A1 + (size_t)rc * 128 + q * 8);
        const short8* a2 = (const short8*)(A2 + (size_t)rc * 128 + q * 8);
        float4v c0 = {0.f, 0.f, 0.f, 0.f}, c1 = {0.f, 0.f, 0.f, 0.f};
        #pragma unroll
        for (int c = 0; c < 4; ++c) {
            short8 a = a1[c * 4];
            c0 = __builtin_amdgcn_mfma_f32_16x16x32_bf16(a, B1[0][c], c0, 0, 0, 0);
            c1 = __builtin_amdgcn_mfma_f32_16x16x32_bf16(a, B1[1][c], c1, 0, 0, 0);
        }
        #pragma unroll
        for (int c = 0; c < 4; ++c) {
            short8 a = a2[c * 4];
            c0 = __builtin_amdgcn_mfma_f32_16x16x32_bf16(a, B2[0][c], c0, 0, 0, 0);
            c1 = __builtin_amdgcn_mfma_f32_16x16x32_bf16(a, B2[1][c], c1, 0, 0, 0);
        }
        #pragma unroll
        for (int r = 0; r < 4; ++r) {
            int ro = rb + rt * 16 + q * 4 + r;
            if (ro < N) {
                float v0 = c0[r] + b0;
                float v1 = c1[r] + b1;
                if (ACT == 0) { v0 = fmaxf(v0, 0.f); v1 = fmaxf(v1, 0.f); }
                else          { v0 = act_leaky_elu(v0); v1 = act_leaky_elu(v1); }
                out[(size_t)ro * 256 + cg + m]      = v0;
                out[(size_t)ro * 256 + cg + 16 + m] = v1;
            }
        }
    }
}

extern "C" void kernel_launch(void* const* d_in, const int* in_sizes, int n_in,
                              void* d_out, int out_size, void* d_ws, size_t ws_size,
                              hipStream_t stream) {
    const float* x    = (const float*)d_in[0];
    const int*   ei   = (const int*)d_in[1];
    const float* ew   = (const float*)d_in[2];
    const float* Wpre = (const float*)d_in[3];
    const float* bpre = (const float*)d_in[4];
    const float* Wai  = (const float*)d_in[5];
    const float* War  = (const float*)d_in[6];
    const float* ab   = (const float*)d_in[7];
    const float* Wsl  = (const float*)d_in[8];
    const float* bsl  = (const float*)d_in[9];
    const float* Wsr  = (const float*)d_in[10];

    const int N = in_sizes[0] / 128;
    const int E = in_sizes[2];
    const size_t NF = (size_t)N * 128;
    const int R = (N + HR - 1) >> HRL2;

    unsigned short* hb  = (unsigned short*)d_ws;  // NF bf16
    unsigned short* agb = hb + NF;                // NF bf16
    unsigned short* mnb = agb + NF;               // NF bf16
    float* dis  = (float*)(mnb + NF);             // N
    int*   cnti = (int*)(dis + N);                // N+1
    int*   rowp = cnti + (N + 1);                 // N+1
    int*   blks = rowp + (N + 1);                 // 128
    int*   rank = blks + 128;                     // E
    int*   part = rank + E;                       // R*NSLICE*HR
    void*  recs = (void*)(part + (size_t)R * NSLICE * HR);  // E uint / E int2

    const bool packed = (N <= (1 << 17));

    const int ge = (E + 255) / 256;
    const int gv = (N + 255) / 256;
    const int gd = (N + 127) / 128;
    const int ns = N + 1;
    const int nb = (ns + 1023) / 1024;

    if (packed) {
        hipMemsetAsync(cnti + N, 0, sizeof(int), stream);  // only cnti[N] needed
        k_hist<<<R * NSLICE, 256, 0, stream>>>(ei + E, rank, part, E, R);
        k_scanS<<<((R << HRL2) + 255) / 256, 256, 0, stream>>>(part, cnti, N, R);
        k_scan1<<<nb, 256, 0, stream>>>(cnti, rowp, blks, ns);
        k_scan2<<<1, 128, 0, stream>>>(blks, nb);
        k_scan3<<<nb, 256, 0, stream>>>(rowp, blks, ns);
        k_scatterP<<<ge, 256, 0, stream>>>(ei, ew, rowp, rank, part,
                                           (unsigned*)recs, E);
        k_degsum<true><<<gv, 256, 0, stream>>>(rowp, recs, dis, N);
    } else {
        hipMemsetAsync(cnti, 0, (N + 1) * sizeof(int), stream);
        k_cnt<<<ge, 256, 0, stream>>>(ei, cnti, rank, E);
        k_scan1<<<nb, 256, 0, stream>>>(cnti, rowp, blks, ns);
        k_scan2<<<1, 128, 0, stream>>>(blks, nb);
        k_scan3<<<nb, 256, 0, stream>>>(rowp, blks, ns);
        k_scatterW<<<ge, 256, 0, stream>>>(ei, ew, rowp, rank, (int2*)recs, E);
        k_degsum<false><<<gv, 256, 0, stream>>>(rowp, recs, dis, N);
    }

    k_pre<<<gd, 256, 0, stream>>>(x, Wpre, bpre, hb, N);

    if (packed)
        k_pull<true><<<(N + 3) / 4, 256, 0, stream>>>(rowp, recs, dis,
            (const uint4*)hb, (uint4*)agb, (uint4*)mnb, N);
    else
        k_pull<false><<<(N + 3) / 4, 256, 0, stream>>>(rowp, recs, dis,
            (const uint4*)hb, (uint4*)agb, (uint4*)mnb, N);

    float* out = (float*)d_out;
    k_final<0><<<gd, 256, 0, stream>>>(agb, hb, Wai, War, ab, out, N);
    k_final<1><<<gd, 256, 0, stream>>>(mnb, hb, Wsl, Wsr, bsl, out + 128, N);
}